// Round 19
// baseline (236.185 us; speedup 1.0000x reference)
//
#include <hip/hip_runtime.h>
#include <hip/hip_bf16.h>
#include <math.h>

#define NW 4   // samples per 256-thread block (1 per wave)

typedef __attribute__((ext_vector_type(8)))  short bf16x8;
typedef __attribute__((ext_vector_type(16))) float f32x16;

__device__ __forceinline__ float bperm(int srcidx, float x) {
    return __int_as_float(__builtin_amdgcn_ds_bpermute(srcidx, __float_as_int(x)));
}
// f32 -> bf16 bits, RNE (manual, bit-deterministic: probes)
__device__ __forceinline__ unsigned f2bfu(float x) {
    unsigned u = __float_as_uint(x);
    return (u + 0x7fffu + ((u >> 16) & 1u)) >> 16;
}
__device__ __forceinline__ float bf2f(unsigned hb) { return __uint_as_float(hb << 16); }
__device__ __forceinline__ unsigned short bfb(float x) {
    __hip_bfloat16 b = __float2bfloat16(x);
    unsigned short u;
    __builtin_memcpy(&u, &b, sizeof(u));
    return u;
}
__device__ __forceinline__ void split(float x, unsigned short& hb, unsigned short& lb) {
    hb = bfb(x);
    float lo = x - bf2f(hb);
    lb = bfb(lo);
}
template <int JM>
__device__ __forceinline__ bf16x8 pick(const unsigned short (&s)[8]) {
    bf16x8 r;
    #pragma unroll
    for (int j = 0; j < 8; ++j) {
        int idx = (JM == 0) ? j : (JM == 1 ? (j ^ 4) : (7 - j));
        r[j] = (short)s[idx];
    }
    return r;
}
// two ds_read_b64 -> one bf16x8 (stride-36 planes: 2-way conflicts = free)
__device__ __forceinline__ bf16x8 rd8(const unsigned short* p) {
    uint2 a = *reinterpret_cast<const uint2*>(p);
    uint2 b = *reinterpret_cast<const uint2*>(p + 4);
    union { unsigned u[4]; bf16x8 v; } r;
    r.u[0] = a.x; r.u[1] = a.y; r.u[2] = b.x; r.u[3] = b.y;
    return r.v;
}

// logm via Chebyshev deg-10 of log on [1,8]: S=(M-4.5I)/3.5, T_{k+1}=2*S*T_k-T_{k-1}.
// A-operand S: hi/lo bf16 split in registers (precision carrier); B-operand T_k:
// bf16-only LDS plane (R16 structure, proven 136us/absmax 0.0, 120 VGPR).
// R18: (1) SPLIT ACCUMULATORS -- hi/lo into separate accs = 4 independent 2-deep
// MFMA chains per wave instead of 2x 4-deep (halves dep latency, costs AGPRs not
// VGPRs); (2) NW=4 / 256-thread blocks, launch_bounds(256,2) (cap 256 >> 120
// needed); (3) per-wave direct atomicAdd (no __syncthreads coupling).
// Layout discovered by 3 one-MFMA probes (proven R10+, absmax 0.0).
__global__ __launch_bounds__(256, 2)
void geo_loss_mfma(const float* __restrict__ yhat, const float* __restrict__ y,
                   float* __restrict__ out, int B)
{
    __shared__ unsigned short TA[NW][32][36];   // chain-1 (yhat) T_k plane, bf16
    __shared__ unsigned short TB[NW][32][36];   // chain-2 (y)    T_k plane, bf16

    const int t    = threadIdx.x;
    const int w    = t >> 6;
    const int lane = t & 63;
    const int c    = lane & 31;
    const int h    = lane >> 5;

    int b = blockIdx.x * NW + w;
    const float valid = (b < B) ? 1.f : 0.f;
    if (b >= B) b = B - 1;

    const f32x16 zz = {0.f,0.f,0.f,0.f,0.f,0.f,0.f,0.f,0.f,0.f,0.f,0.f,0.f,0.f,0.f,0.f};
    float sent = 0.f;

    // ---- probe 1: relative A/B slot-labeling delta (6 hypotheses) ----
    bf16x8 pa;
    #pragma unroll
    for (int j = 0; j < 8; ++j) pa[j] = (short)f2bfu((float)(8*h + j + 1));
    int sel = -1;
    #pragma unroll
    for (int cand = 0; cand < 6; ++cand) {
        const int hfc = cand & 1, jmc = cand >> 1;
        bf16x8 pb;
        #pragma unroll
        for (int j = 0; j < 8; ++j) {
            int hh = hfc ? (1 - h) : h;
            int jj = (jmc == 0) ? j : (jmc == 1 ? (j ^ 4) : (7 - j));
            float lab = (float)(8*hh + jj + 1);
            pb[j] = (short)f2bfu(lab * lab);
        }
        f32x16 pr = __builtin_amdgcn_mfma_f32_32x32x16_bf16(pa, pb, zz, 0, 0, 0);
        if (sel < 0 && __ballot(pr[0] != 18496.f) == 0ull) sel = cand;
    }
    if (sel < 0) { sent += 1.0e10f; sel = 0; }
    const int hf = sel & 1, jm = sel >> 1;

    // ---- probe 2: C (lane,reg) -> row map (init-only) ----
    bf16x8 pa2, pb1;
    #pragma unroll
    for (int j = 0; j < 8; ++j) {
        pa2[j] = (short)f2bfu((float)(c + 1));
        pb1[j] = (short)f2bfu(1.f);
    }
    f32x16 r2 = __builtin_amdgcn_mfma_f32_32x32x16_bf16(pa2, pb1, zz, 0, 0, 0);
    int rws[16]; bool ok2 = true;
    #pragma unroll
    for (int i = 0; i < 16; ++i) {
        float q = r2[i] * 0.0625f;
        int ri = (int)(q + 0.5f);
        ok2 = ok2 && (fabsf(q - (float)ri) < 1e-3f) && ri >= 1 && ri <= 32;
        rws[i] = ri - 1;
    }
    if (__ballot(!ok2) != 0ull) {
        sent += 2.0e10f;
        #pragma unroll
        for (int i = 0; i < 16; ++i) rws[i] = (i & 3) + 8*(i >> 2) + 4*h;
    }

    // ---- probe 3: C lane -> col map ----
    f32x16 r3 = __builtin_amdgcn_mfma_f32_32x32x16_bf16(pb1, pa2, zz, 0, 0, 0);
    int colstar;
    {
        float q = r3[0] * 0.0625f;
        int ci = (int)(q + 0.5f);
        bool ok3 = (fabsf(q - (float)ci) < 1e-3f) && ci >= 1 && ci <= 32;
        colstar = ci - 1;
        if (__ballot(!ok3) != 0ull) { sent += 4.0e10f; colstar = c; }
    }

    // quad-contiguity; keep only rq[4] live through the loop
    bool qok = true;
    int rq[4];
    #pragma unroll
    for (int q = 0; q < 4; ++q) {
        rq[q] = rws[4*q];
        qok = qok && ((rws[4*q] & 3) == 0) && (rws[4*q+1] == rws[4*q]+1)
                  && (rws[4*q+2] == rws[4*q]+2) && (rws[4*q+3] == rws[4*q]+3);
    }
    if (__ballot(!qok) != 0ull) {
        sent += 8.0e10f;
        #pragma unroll
        for (int q = 0; q < 4; ++q) rq[q] = 8*q + 4*h;
    }
    if (lane == 0 && sent > 0.f) atomicAdd(out, sent);

    const float INV = 0.2857142857142857f;   // 1/3.5
    const int abase = 8 * (h ^ hf);

    // ---- load S rows; A-frags hi/lo in regs; stage bf16 S (=T1) to planes ----
    bf16x8 A1h0, A1l0, A1h1, A1l1, A2h0, A2l0, A2h1, A2l1;
    #pragma unroll
    for (int m = 0; m < 2; ++m) {
        const float* Mp = (m == 0 ? yhat : y) + ((size_t)b << 10);
        unsigned short H0[8], L0[8], H1[8], L1[8];
        const float4* p0 = reinterpret_cast<const float4*>(Mp + c*32 + abase);
        float4 q0 = p0[0], q1 = p0[1];
        float f0[8] = {q0.x,q0.y,q0.z,q0.w, q1.x,q1.y,q1.z,q1.w};
        const float4* p1 = reinterpret_cast<const float4*>(Mp + c*32 + 16 + abase);
        float4 q2 = p1[0], q3 = p1[1];
        float f1[8] = {q2.x,q2.y,q2.z,q2.w, q3.x,q3.y,q3.z,q3.w};
        #pragma unroll
        for (int e = 0; e < 8; ++e) {
            int k0 = abase + e, k1 = 16 + abase + e;
            float x0 = (f0[e] - ((k0 == c) ? 4.5f : 0.f)) * INV;
            float x1 = (f1[e] - ((k1 == c) ? 4.5f : 0.f)) * INV;
            split(x0, H0[e], L0[e]);
            split(x1, H1[e], L1[e]);
        }
        unsigned short (*pl)[36] = (m == 0) ? TA[w] : TB[w];
        *reinterpret_cast<uint2*>(&pl[c][abase]) =
            make_uint2((unsigned)H0[0] | ((unsigned)H0[1] << 16),
                       (unsigned)H0[2] | ((unsigned)H0[3] << 16));
        *reinterpret_cast<uint2*>(&pl[c][abase + 4]) =
            make_uint2((unsigned)H0[4] | ((unsigned)H0[5] << 16),
                       (unsigned)H0[6] | ((unsigned)H0[7] << 16));
        *reinterpret_cast<uint2*>(&pl[c][16 + abase]) =
            make_uint2((unsigned)H1[0] | ((unsigned)H1[1] << 16),
                       (unsigned)H1[2] | ((unsigned)H1[3] << 16));
        *reinterpret_cast<uint2*>(&pl[c][16 + abase + 4]) =
            make_uint2((unsigned)H1[4] | ((unsigned)H1[5] << 16),
                       (unsigned)H1[6] | ((unsigned)H1[7] << 16));
        bf16x8 ah0, al0, ah1, al1;
        if (jm == 0)      { ah0=pick<0>(H0); al0=pick<0>(L0); ah1=pick<0>(H1); al1=pick<0>(L1); }
        else if (jm == 1) { ah0=pick<1>(H0); al0=pick<1>(L0); ah1=pick<1>(H1); al1=pick<1>(L1); }
        else              { ah0=pick<2>(H0); al0=pick<2>(L0); ah1=pick<2>(H1); al1=pick<2>(L1); }
        if (m == 0) { A1h0=ah0; A1l0=al0; A1h1=ah1; A1l1=al1; }
        else        { A2h0=ah0; A2l0=al0; A2h1=ah1; A2l1=al1; }
    }

    // ---- init recurrence state (T1 = S from plane, bf16 precision) ----
    float U1[16], V1[16], P1[16], U2[16], V2[16], P2[16];
    #pragma unroll
    for (int i = 0; i < 16; ++i) {
        float dg = (rws[i] == colstar) ? 1.f : 0.f;
        float tv1 = bf2f(TA[w][colstar][rws[i]]);
        float tv2 = bf2f(TB[w][colstar][rws[i]]);
        V1[i] = tv1; V2[i] = tv2; U1[i] = dg; U2[i] = dg;
        P1[i] = fmaf(0.95518452f, tv1, 1.2986135f * dg);
        P2[i] = fmaf(0.95518452f, tv2, 1.2986135f * dg);
    }

    // dual-chain Chebyshev step, SPLIT ACCUMULATORS: 4 independent 2-deep MFMA
    // chains (a1h,a1l,a2h,a2l); merge n = 2*(ah+al) - W via two fma.
    auto STEP = [&](float coef, float (&W1)[16], float (&W2)[16], bool dostore) {
        bf16x8 B10 = rd8(&TA[w][c][8*h]);
        bf16x8 B11 = rd8(&TA[w][c][16 + 8*h]);
        bf16x8 B20 = rd8(&TB[w][c][8*h]);
        bf16x8 B21 = rd8(&TB[w][c][16 + 8*h]);
        f32x16 a1h = zz, a1l = zz, a2h = zz, a2l = zz;
        a1h = __builtin_amdgcn_mfma_f32_32x32x16_bf16(A1h0, B10, a1h, 0,0,0);
        a1l = __builtin_amdgcn_mfma_f32_32x32x16_bf16(A1l0, B10, a1l, 0,0,0);
        a2h = __builtin_amdgcn_mfma_f32_32x32x16_bf16(A2h0, B20, a2h, 0,0,0);
        a2l = __builtin_amdgcn_mfma_f32_32x32x16_bf16(A2l0, B20, a2l, 0,0,0);
        a1h = __builtin_amdgcn_mfma_f32_32x32x16_bf16(A1h1, B11, a1h, 0,0,0);
        a1l = __builtin_amdgcn_mfma_f32_32x32x16_bf16(A1l1, B11, a1l, 0,0,0);
        a2h = __builtin_amdgcn_mfma_f32_32x32x16_bf16(A2h1, B21, a2h, 0,0,0);
        a2l = __builtin_amdgcn_mfma_f32_32x32x16_bf16(A2l1, B21, a2l, 0,0,0);
        #pragma unroll
        for (int i = 0; i < 16; ++i) {
            float n1 = fmaf(2.f, a1h[i], fmaf(2.f, a1l[i], -W1[i]));
            float n2 = fmaf(2.f, a2h[i], fmaf(2.f, a2l[i], -W2[i]));
            W1[i] = n1; W2[i] = n2;
            P1[i] = fmaf(coef, n1, P1[i]);
            P2[i] = fmaf(coef, n2, P2[i]);
        }
        if (dostore) {
            #pragma unroll
            for (int q = 0; q < 4; ++q) {
                int r0 = rq[q];
                unsigned short b1[4], b2[4];
                #pragma unroll
                for (int e = 0; e < 4; ++e) {
                    b1[e] = bfb(W1[4*q+e]);
                    b2[e] = bfb(W2[4*q+e]);
                }
                *reinterpret_cast<uint2*>(&TA[w][colstar][r0]) =
                    make_uint2((unsigned)b1[0] | ((unsigned)b1[1] << 16),
                               (unsigned)b1[2] | ((unsigned)b1[3] << 16));
                *reinterpret_cast<uint2*>(&TB[w][colstar][r0]) =
                    make_uint2((unsigned)b2[0] | ((unsigned)b2[1] << 16),
                               (unsigned)b2[2] | ((unsigned)b2[3] << 16));
            }
        }
    };

    STEP(-0.22809412f, U1, U2, true);    // T2
    STEP( 0.07262391f, V1, V2, true);    // T3
    STEP(-0.02601347f, U1, U2, true);    // T4
    STEP( 0.00993906f, V1, V2, true);    // T5
    STEP(-0.00395568f, U1, U2, true);    // T6
    STEP( 0.00161931f, V1, V2, true);    // T7
    STEP(-0.00067670f, U1, U2, true);    // T8
    STEP( 0.00028728f, V1, V2, true);    // T9
    STEP(-0.00012348f, U1, U2, false);   // T10 (T11,T12 dropped: <=8e-5/eig, proven R17)

    // ---- loss: per-wave reduce + direct atomic (no block barrier) ----
    float s = 0.f;
    #pragma unroll
    for (int i = 0; i < 16; ++i) { float d = P1[i] - P2[i]; s = fmaf(d, d, s); }
    #pragma unroll
    for (int m = 32; m >= 1; m >>= 1)
        s += bperm((lane ^ m) << 2, s);
    if (lane == 0) atomicAdd(out, valid * sqrtf(fmaxf(s, 0.f)));
}

extern "C" void kernel_launch(void* const* d_in, const int* in_sizes, int n_in,
                              void* d_out, int out_size, void* d_ws, size_t ws_size,
                              hipStream_t stream)
{
    const float* yhat = (const float*)d_in[0];
    const float* y    = (const float*)d_in[1];
    float* out = (float*)d_out;
    const int B = in_sizes[0] / 1024;   // 32*32 per matrix

    (void)hipMemsetAsync(out, 0, sizeof(float), stream);
    const int grid = (B + NW - 1) / NW;
    hipLaunchKernelGGL(geo_loss_mfma, dim3(grid), dim3(256), 0, stream,
                       yhat, y, out, B);
}

// Round 20
// 234.706 us; speedup vs baseline: 1.0063x; 1.0063x over previous
//
#include <hip/hip_runtime.h>
#include <hip/hip_bf16.h>
#include <math.h>

#define NW 2   // samples per 128-thread block (1 per wave)

typedef __attribute__((ext_vector_type(8)))  short bf16x8;
typedef __attribute__((ext_vector_type(16))) float f32x16;

__device__ __forceinline__ float bperm(int srcidx, float x) {
    return __int_as_float(__builtin_amdgcn_ds_bpermute(srcidx, __float_as_int(x)));
}
// f32 -> bf16 bits, RNE (manual, bit-deterministic: probes)
__device__ __forceinline__ unsigned f2bfu(float x) {
    unsigned u = __float_as_uint(x);
    return (u + 0x7fffu + ((u >> 16) & 1u)) >> 16;
}
__device__ __forceinline__ float bf2f(unsigned hb) { return __uint_as_float(hb << 16); }
__device__ __forceinline__ unsigned short bfb(float x) {
    __hip_bfloat16 b = __float2bfloat16(x);
    unsigned short u;
    __builtin_memcpy(&u, &b, sizeof(u));
    return u;
}
__device__ __forceinline__ void split(float x, unsigned short& hb, unsigned short& lb) {
    hb = bfb(x);
    float lo = x - bf2f(hb);
    lb = bfb(lo);
}
template <int JM>
__device__ __forceinline__ bf16x8 pick(const unsigned short (&s)[8]) {
    bf16x8 r;
    #pragma unroll
    for (int j = 0; j < 8; ++j) {
        int idx = (JM == 0) ? j : (JM == 1 ? (j ^ 4) : (7 - j));
        r[j] = (short)s[idx];
    }
    return r;
}
// two ds_read_b64 -> one bf16x8 (stride-36 planes: 2-way conflicts = free)
__device__ __forceinline__ bf16x8 rd8(const unsigned short* p) {
    uint2 a = *reinterpret_cast<const uint2*>(p);
    uint2 b = *reinterpret_cast<const uint2*>(p + 4);
    union { unsigned u[4]; bf16x8 v; } r;
    r.u[0] = a.x; r.u[1] = a.y; r.u[2] = b.x; r.u[3] = b.y;
    return r.v;
}

// logm via Chebyshev deg-10 of log on [1,8]: S=(M-4.5I)/3.5, T_{k+1}=2*S*T_k-T_{k-1}.
// A-operand S: hi/lo bf16 split in registers (precision carrier); B-operand T_k:
// bf16-only LDS plane (R16 structure, proven 136us/absmax 0.0, 120 VGPR).
// R19 consolidation at the latency plateau: (1) 9 STEPs (T11 dropped, proven);
// (2) only the DIFFERENCE D = P1-P2 accumulated (c0/diag cancel exactly; -16 VGPR);
// (3) store-before-accumulate (D-fma off the store->next-read critical path);
// (4) per-wave direct atomicAdd. Single acc per matrix (R18's 4-acc split
// regressed 2x via AGPR copy traffic). Layout probes: proven R10+, absmax 0.0.
__global__ __launch_bounds__(128, 1)
void geo_loss_mfma(const float* __restrict__ yhat, const float* __restrict__ y,
                   float* __restrict__ out, int B)
{
    __shared__ unsigned short TA[NW][32][36];   // chain-1 (yhat) T_k plane, bf16
    __shared__ unsigned short TB[NW][32][36];   // chain-2 (y)    T_k plane, bf16

    const int t    = threadIdx.x;
    const int w    = t >> 6;
    const int lane = t & 63;
    const int c    = lane & 31;
    const int h    = lane >> 5;

    int b = blockIdx.x * NW + w;
    const float valid = (b < B) ? 1.f : 0.f;
    if (b >= B) b = B - 1;

    const f32x16 zz = {0.f,0.f,0.f,0.f,0.f,0.f,0.f,0.f,0.f,0.f,0.f,0.f,0.f,0.f,0.f,0.f};
    float sent = 0.f;

    // ---- probe 1: relative A/B slot-labeling delta (6 hypotheses) ----
    bf16x8 pa;
    #pragma unroll
    for (int j = 0; j < 8; ++j) pa[j] = (short)f2bfu((float)(8*h + j + 1));
    int sel = -1;
    #pragma unroll
    for (int cand = 0; cand < 6; ++cand) {
        const int hfc = cand & 1, jmc = cand >> 1;
        bf16x8 pb;
        #pragma unroll
        for (int j = 0; j < 8; ++j) {
            int hh = hfc ? (1 - h) : h;
            int jj = (jmc == 0) ? j : (jmc == 1 ? (j ^ 4) : (7 - j));
            float lab = (float)(8*hh + jj + 1);
            pb[j] = (short)f2bfu(lab * lab);
        }
        f32x16 pr = __builtin_amdgcn_mfma_f32_32x32x16_bf16(pa, pb, zz, 0, 0, 0);
        if (sel < 0 && __ballot(pr[0] != 18496.f) == 0ull) sel = cand;
    }
    if (sel < 0) { sent += 1.0e10f; sel = 0; }
    const int hf = sel & 1, jm = sel >> 1;

    // ---- probe 2: C (lane,reg) -> row map (init-only) ----
    bf16x8 pa2, pb1;
    #pragma unroll
    for (int j = 0; j < 8; ++j) {
        pa2[j] = (short)f2bfu((float)(c + 1));
        pb1[j] = (short)f2bfu(1.f);
    }
    f32x16 r2 = __builtin_amdgcn_mfma_f32_32x32x16_bf16(pa2, pb1, zz, 0, 0, 0);
    int rws[16]; bool ok2 = true;
    #pragma unroll
    for (int i = 0; i < 16; ++i) {
        float q = r2[i] * 0.0625f;
        int ri = (int)(q + 0.5f);
        ok2 = ok2 && (fabsf(q - (float)ri) < 1e-3f) && ri >= 1 && ri <= 32;
        rws[i] = ri - 1;
    }
    if (__ballot(!ok2) != 0ull) {
        sent += 2.0e10f;
        #pragma unroll
        for (int i = 0; i < 16; ++i) rws[i] = (i & 3) + 8*(i >> 2) + 4*h;
    }

    // ---- probe 3: C lane -> col map ----
    f32x16 r3 = __builtin_amdgcn_mfma_f32_32x32x16_bf16(pb1, pa2, zz, 0, 0, 0);
    int colstar;
    {
        float q = r3[0] * 0.0625f;
        int ci = (int)(q + 0.5f);
        bool ok3 = (fabsf(q - (float)ci) < 1e-3f) && ci >= 1 && ci <= 32;
        colstar = ci - 1;
        if (__ballot(!ok3) != 0ull) { sent += 4.0e10f; colstar = c; }
    }

    // quad-contiguity; keep only rq[4] live through the loop
    bool qok = true;
    int rq[4];
    #pragma unroll
    for (int q = 0; q < 4; ++q) {
        rq[q] = rws[4*q];
        qok = qok && ((rws[4*q] & 3) == 0) && (rws[4*q+1] == rws[4*q]+1)
                  && (rws[4*q+2] == rws[4*q]+2) && (rws[4*q+3] == rws[4*q]+3);
    }
    if (__ballot(!qok) != 0ull) {
        sent += 8.0e10f;
        #pragma unroll
        for (int q = 0; q < 4; ++q) rq[q] = 8*q + 4*h;
    }
    if (lane == 0 && sent > 0.f) atomicAdd(out, sent);

    const float INV = 0.2857142857142857f;   // 1/3.5
    const int abase = 8 * (h ^ hf);

    // ---- load S rows; A-frags hi/lo in regs; stage bf16 S (=T1) to planes ----
    bf16x8 A1h0, A1l0, A1h1, A1l1, A2h0, A2l0, A2h1, A2l1;
    #pragma unroll
    for (int m = 0; m < 2; ++m) {
        const float* Mp = (m == 0 ? yhat : y) + ((size_t)b << 10);
        unsigned short H0[8], L0[8], H1[8], L1[8];
        const float4* p0 = reinterpret_cast<const float4*>(Mp + c*32 + abase);
        float4 q0 = p0[0], q1 = p0[1];
        float f0[8] = {q0.x,q0.y,q0.z,q0.w, q1.x,q1.y,q1.z,q1.w};
        const float4* p1 = reinterpret_cast<const float4*>(Mp + c*32 + 16 + abase);
        float4 q2 = p1[0], q3 = p1[1];
        float f1[8] = {q2.x,q2.y,q2.z,q2.w, q3.x,q3.y,q3.z,q3.w};
        #pragma unroll
        for (int e = 0; e < 8; ++e) {
            int k0 = abase + e, k1 = 16 + abase + e;
            float x0 = (f0[e] - ((k0 == c) ? 4.5f : 0.f)) * INV;
            float x1 = (f1[e] - ((k1 == c) ? 4.5f : 0.f)) * INV;
            split(x0, H0[e], L0[e]);
            split(x1, H1[e], L1[e]);
        }
        unsigned short (*pl)[36] = (m == 0) ? TA[w] : TB[w];
        *reinterpret_cast<uint2*>(&pl[c][abase]) =
            make_uint2((unsigned)H0[0] | ((unsigned)H0[1] << 16),
                       (unsigned)H0[2] | ((unsigned)H0[3] << 16));
        *reinterpret_cast<uint2*>(&pl[c][abase + 4]) =
            make_uint2((unsigned)H0[4] | ((unsigned)H0[5] << 16),
                       (unsigned)H0[6] | ((unsigned)H0[7] << 16));
        *reinterpret_cast<uint2*>(&pl[c][16 + abase]) =
            make_uint2((unsigned)H1[0] | ((unsigned)H1[1] << 16),
                       (unsigned)H1[2] | ((unsigned)H1[3] << 16));
        *reinterpret_cast<uint2*>(&pl[c][16 + abase + 4]) =
            make_uint2((unsigned)H1[4] | ((unsigned)H1[5] << 16),
                       (unsigned)H1[6] | ((unsigned)H1[7] << 16));
        bf16x8 ah0, al0, ah1, al1;
        if (jm == 0)      { ah0=pick<0>(H0); al0=pick<0>(L0); ah1=pick<0>(H1); al1=pick<0>(L1); }
        else if (jm == 1) { ah0=pick<1>(H0); al0=pick<1>(L0); ah1=pick<1>(H1); al1=pick<1>(L1); }
        else              { ah0=pick<2>(H0); al0=pick<2>(L0); ah1=pick<2>(H1); al1=pick<2>(L1); }
        if (m == 0) { A1h0=ah0; A1l0=al0; A1h1=ah1; A1l1=al1; }
        else        { A2h0=ah0; A2l0=al0; A2h1=ah1; A2l1=al1; }
    }

    // ---- init recurrence state; only the DIFFERENCE D = P1-P2 is tracked
    // (c0*I and c1-diag contributions cancel exactly in the difference) ----
    float U1[16], V1[16], U2[16], V2[16], D[16];
    #pragma unroll
    for (int i = 0; i < 16; ++i) {
        float dg = (rws[i] == colstar) ? 1.f : 0.f;
        float tv1 = bf2f(TA[w][colstar][rws[i]]);
        float tv2 = bf2f(TB[w][colstar][rws[i]]);
        V1[i] = tv1; V2[i] = tv2; U1[i] = dg; U2[i] = dg;
        D[i] = 0.95518452f * (tv1 - tv2);
    }

    // dual-chain Chebyshev step (R16-proven MFMA pattern, single acc per matrix).
    // Order: read B -> MFMA -> recurrence -> STORE (critical path) -> D-accum.
    auto STEP = [&](float coef, float (&W1)[16], float (&W2)[16], bool dostore) {
        bf16x8 B10 = rd8(&TA[w][c][8*h]);
        bf16x8 B11 = rd8(&TA[w][c][16 + 8*h]);
        bf16x8 B20 = rd8(&TB[w][c][8*h]);
        bf16x8 B21 = rd8(&TB[w][c][16 + 8*h]);
        f32x16 a1 = zz, a2 = zz;
        a1 = __builtin_amdgcn_mfma_f32_32x32x16_bf16(A1h0, B10, a1, 0,0,0);
        a2 = __builtin_amdgcn_mfma_f32_32x32x16_bf16(A2h0, B20, a2, 0,0,0);
        a1 = __builtin_amdgcn_mfma_f32_32x32x16_bf16(A1l0, B10, a1, 0,0,0);
        a2 = __builtin_amdgcn_mfma_f32_32x32x16_bf16(A2l0, B20, a2, 0,0,0);
        a1 = __builtin_amdgcn_mfma_f32_32x32x16_bf16(A1h1, B11, a1, 0,0,0);
        a2 = __builtin_amdgcn_mfma_f32_32x32x16_bf16(A2h1, B21, a2, 0,0,0);
        a1 = __builtin_amdgcn_mfma_f32_32x32x16_bf16(A1l1, B11, a1, 0,0,0);
        a2 = __builtin_amdgcn_mfma_f32_32x32x16_bf16(A2l1, B21, a2, 0,0,0);
        #pragma unroll
        for (int i = 0; i < 16; ++i) {
            W1[i] = fmaf(2.f, a1[i], -W1[i]);
            W2[i] = fmaf(2.f, a2[i], -W2[i]);
        }
        if (dostore) {
            #pragma unroll
            for (int q = 0; q < 4; ++q) {
                int r0 = rq[q];
                unsigned short b1[4], b2[4];
                #pragma unroll
                for (int e = 0; e < 4; ++e) {
                    b1[e] = bfb(W1[4*q+e]);
                    b2[e] = bfb(W2[4*q+e]);
                }
                *reinterpret_cast<uint2*>(&TA[w][colstar][r0]) =
                    make_uint2((unsigned)b1[0] | ((unsigned)b1[1] << 16),
                               (unsigned)b1[2] | ((unsigned)b1[3] << 16));
                *reinterpret_cast<uint2*>(&TB[w][colstar][r0]) =
                    make_uint2((unsigned)b2[0] | ((unsigned)b2[1] << 16),
                               (unsigned)b2[2] | ((unsigned)b2[3] << 16));
            }
        }
        #pragma unroll
        for (int i = 0; i < 16; ++i)
            D[i] = fmaf(coef, W1[i] - W2[i], D[i]);   // off the critical path
    };

    STEP(-0.22809412f, U1, U2, true);    // T2
    STEP( 0.07262391f, V1, V2, true);    // T3
    STEP(-0.02601347f, U1, U2, true);    // T4
    STEP( 0.00993906f, V1, V2, true);    // T5
    STEP(-0.00395568f, U1, U2, true);    // T6
    STEP( 0.00161931f, V1, V2, true);    // T7
    STEP(-0.00067670f, U1, U2, true);    // T8
    STEP( 0.00028728f, V1, V2, true);    // T9
    STEP(-0.00012348f, U1, U2, false);   // T10 (T11,T12 dropped: <=8e-5/eig, proven)

    // ---- loss: per-wave reduce + direct atomic (no block barrier) ----
    float s = 0.f;
    #pragma unroll
    for (int i = 0; i < 16; ++i) s = fmaf(D[i], D[i], s);
    #pragma unroll
    for (int m = 32; m >= 1; m >>= 1)
        s += bperm((lane ^ m) << 2, s);
    if (lane == 0) atomicAdd(out, valid * sqrtf(fmaxf(s, 0.f)));
}

extern "C" void kernel_launch(void* const* d_in, const int* in_sizes, int n_in,
                              void* d_out, int out_size, void* d_ws, size_t ws_size,
                              hipStream_t stream)
{
    const float* yhat = (const float*)d_in[0];
    const float* y    = (const float*)d_in[1];
    float* out = (float*)d_out;
    const int B = in_sizes[0] / 1024;   // 32*32 per matrix

    (void)hipMemsetAsync(out, 0, sizeof(float), stream);
    const int grid = (B + NW - 1) / NW;
    hipLaunchKernelGGL(geo_loss_mfma, dim3(grid), dim3(128), 0, stream,
                       yhat, y, out, B);
}

// Round 21
// 99.904 us; speedup vs baseline: 2.3641x; 2.3493x over previous
//
#include <hip/hip_runtime.h>
#include <hip/hip_bf16.h>
#include <math.h>

#define NW 2   // samples per 128-thread block (1 per wave)

typedef __attribute__((ext_vector_type(8)))  short bf16x8;
typedef __attribute__((ext_vector_type(16))) float f32x16;

__device__ __forceinline__ float bperm(int srcidx, float x) {
    return __int_as_float(__builtin_amdgcn_ds_bpermute(srcidx, __float_as_int(x)));
}
// f32 -> bf16 bits, RNE (manual, bit-deterministic: probes)
__device__ __forceinline__ unsigned f2bfu(float x) {
    unsigned u = __float_as_uint(x);
    return (u + 0x7fffu + ((u >> 16) & 1u)) >> 16;
}
__device__ __forceinline__ float bf2f(unsigned hb) { return __uint_as_float(hb << 16); }
__device__ __forceinline__ unsigned short bfb(float x) {
    __hip_bfloat16 b = __float2bfloat16(x);
    unsigned short u;
    __builtin_memcpy(&u, &b, sizeof(u));
    return u;
}
__device__ __forceinline__ void split(float x, unsigned short& hb, unsigned short& lb) {
    hb = bfb(x);
    float lo = x - bf2f(hb);
    lb = bfb(lo);
}
template <int JM>
__device__ __forceinline__ bf16x8 pick(const unsigned short (&s)[8]) {
    bf16x8 r;
    #pragma unroll
    for (int j = 0; j < 8; ++j) {
        int idx = (JM == 0) ? j : (JM == 1 ? (j ^ 4) : (7 - j));
        r[j] = (short)s[idx];
    }
    return r;
}
// two ds_read_b64 -> one bf16x8 (stride-36 planes: 2-way conflicts = free)
__device__ __forceinline__ bf16x8 rd8(const unsigned short* p) {
    uint2 a = *reinterpret_cast<const uint2*>(p);
    uint2 b = *reinterpret_cast<const uint2*>(p + 4);
    union { unsigned u[4]; bf16x8 v; } r;
    r.u[0] = a.x; r.u[1] = a.y; r.u[2] = b.x; r.u[3] = b.y;
    return r.v;
}

// logm via Chebyshev deg-11 of log on [1,8]: S=(M-4.5I)/3.5, T_{k+1}=2*S*T_k-T_{k-1}.
// EXACT R16 structure (proven 136.7us, absmax 0.0, 120 VGPR). R20's ONE change:
// per-block partial -> ws[] plain store + tiny reduce kernel, replacing the
// same-address atomicAdd. Theory: R14-R19 times fit a serialized same-address
// atomic floor (~14ns/RMW: 8192 atomics=117us, 16384=234us) — NOT compute.
__global__ __launch_bounds__(128, 1)
void geo_loss_mfma(const float* __restrict__ yhat, const float* __restrict__ y,
                   float* __restrict__ out, float* __restrict__ part, int B)
{
    __shared__ unsigned short TA[NW][32][36];   // chain-1 (yhat) T_k plane, bf16
    __shared__ unsigned short TB[NW][32][36];   // chain-2 (y)    T_k plane, bf16
    __shared__ float bl[NW];

    const int t    = threadIdx.x;
    const int w    = t >> 6;
    const int lane = t & 63;
    const int c    = lane & 31;
    const int h    = lane >> 5;

    int b = blockIdx.x * NW + w;
    const float valid = (b < B) ? 1.f : 0.f;
    if (b >= B) b = B - 1;

    const f32x16 zz = {0.f,0.f,0.f,0.f,0.f,0.f,0.f,0.f,0.f,0.f,0.f,0.f,0.f,0.f,0.f,0.f};
    float sent = 0.f;

    // ---- probe 1: relative A/B slot-labeling delta (6 hypotheses) ----
    bf16x8 pa;
    #pragma unroll
    for (int j = 0; j < 8; ++j) pa[j] = (short)f2bfu((float)(8*h + j + 1));
    int sel = -1;
    #pragma unroll
    for (int cand = 0; cand < 6; ++cand) {
        const int hfc = cand & 1, jmc = cand >> 1;
        bf16x8 pb;
        #pragma unroll
        for (int j = 0; j < 8; ++j) {
            int hh = hfc ? (1 - h) : h;
            int jj = (jmc == 0) ? j : (jmc == 1 ? (j ^ 4) : (7 - j));
            float lab = (float)(8*hh + jj + 1);
            pb[j] = (short)f2bfu(lab * lab);
        }
        f32x16 pr = __builtin_amdgcn_mfma_f32_32x32x16_bf16(pa, pb, zz, 0, 0, 0);
        if (sel < 0 && __ballot(pr[0] != 18496.f) == 0ull) sel = cand;
    }
    if (sel < 0) { sent += 1.0e10f; sel = 0; }
    const int hf = sel & 1, jm = sel >> 1;

    // ---- probe 2: C (lane,reg) -> row map (init-only) ----
    bf16x8 pa2, pb1;
    #pragma unroll
    for (int j = 0; j < 8; ++j) {
        pa2[j] = (short)f2bfu((float)(c + 1));
        pb1[j] = (short)f2bfu(1.f);
    }
    f32x16 r2 = __builtin_amdgcn_mfma_f32_32x32x16_bf16(pa2, pb1, zz, 0, 0, 0);
    int rws[16]; bool ok2 = true;
    #pragma unroll
    for (int i = 0; i < 16; ++i) {
        float q = r2[i] * 0.0625f;
        int ri = (int)(q + 0.5f);
        ok2 = ok2 && (fabsf(q - (float)ri) < 1e-3f) && ri >= 1 && ri <= 32;
        rws[i] = ri - 1;
    }
    if (__ballot(!ok2) != 0ull) {
        sent += 2.0e10f;
        #pragma unroll
        for (int i = 0; i < 16; ++i) rws[i] = (i & 3) + 8*(i >> 2) + 4*h;
    }

    // ---- probe 3: C lane -> col map ----
    f32x16 r3 = __builtin_amdgcn_mfma_f32_32x32x16_bf16(pb1, pa2, zz, 0, 0, 0);
    int colstar;
    {
        float q = r3[0] * 0.0625f;
        int ci = (int)(q + 0.5f);
        bool ok3 = (fabsf(q - (float)ci) < 1e-3f) && ci >= 1 && ci <= 32;
        colstar = ci - 1;
        if (__ballot(!ok3) != 0ull) { sent += 4.0e10f; colstar = c; }
    }

    // quad-contiguity; keep only rq[4] live through the loop
    bool qok = true;
    int rq[4];
    #pragma unroll
    for (int q = 0; q < 4; ++q) {
        rq[q] = rws[4*q];
        qok = qok && ((rws[4*q] & 3) == 0) && (rws[4*q+1] == rws[4*q]+1)
                  && (rws[4*q+2] == rws[4*q]+2) && (rws[4*q+3] == rws[4*q]+3);
    }
    if (__ballot(!qok) != 0ull) {
        sent += 8.0e10f;
        #pragma unroll
        for (int q = 0; q < 4; ++q) rq[q] = 8*q + 4*h;
    }
    if (lane == 0 && sent > 0.f) atomicAdd(out, sent);   // cold path only

    const float INV = 0.2857142857142857f;   // 1/3.5
    const int abase = 8 * (h ^ hf);

    // ---- load S rows; A-frags hi/lo in regs; stage bf16 S (=T1) to planes ----
    bf16x8 A1h0, A1l0, A1h1, A1l1, A2h0, A2l0, A2h1, A2l1;
    #pragma unroll
    for (int m = 0; m < 2; ++m) {
        const float* Mp = (m == 0 ? yhat : y) + ((size_t)b << 10);
        unsigned short H0[8], L0[8], H1[8], L1[8];
        const float4* p0 = reinterpret_cast<const float4*>(Mp + c*32 + abase);
        float4 q0 = p0[0], q1 = p0[1];
        float f0[8] = {q0.x,q0.y,q0.z,q0.w, q1.x,q1.y,q1.z,q1.w};
        const float4* p1 = reinterpret_cast<const float4*>(Mp + c*32 + 16 + abase);
        float4 q2 = p1[0], q3 = p1[1];
        float f1[8] = {q2.x,q2.y,q2.z,q2.w, q3.x,q3.y,q3.z,q3.w};
        #pragma unroll
        for (int e = 0; e < 8; ++e) {
            int k0 = abase + e, k1 = 16 + abase + e;
            float x0 = (f0[e] - ((k0 == c) ? 4.5f : 0.f)) * INV;
            float x1 = (f1[e] - ((k1 == c) ? 4.5f : 0.f)) * INV;
            split(x0, H0[e], L0[e]);
            split(x1, H1[e], L1[e]);
        }
        unsigned short (*pl)[36] = (m == 0) ? TA[w] : TB[w];
        *reinterpret_cast<uint2*>(&pl[c][abase]) =
            make_uint2((unsigned)H0[0] | ((unsigned)H0[1] << 16),
                       (unsigned)H0[2] | ((unsigned)H0[3] << 16));
        *reinterpret_cast<uint2*>(&pl[c][abase + 4]) =
            make_uint2((unsigned)H0[4] | ((unsigned)H0[5] << 16),
                       (unsigned)H0[6] | ((unsigned)H0[7] << 16));
        *reinterpret_cast<uint2*>(&pl[c][16 + abase]) =
            make_uint2((unsigned)H1[0] | ((unsigned)H1[1] << 16),
                       (unsigned)H1[2] | ((unsigned)H1[3] << 16));
        *reinterpret_cast<uint2*>(&pl[c][16 + abase + 4]) =
            make_uint2((unsigned)H1[4] | ((unsigned)H1[5] << 16),
                       (unsigned)H1[6] | ((unsigned)H1[7] << 16));
        bf16x8 ah0, al0, ah1, al1;
        if (jm == 0)      { ah0=pick<0>(H0); al0=pick<0>(L0); ah1=pick<0>(H1); al1=pick<0>(L1); }
        else if (jm == 1) { ah0=pick<1>(H0); al0=pick<1>(L0); ah1=pick<1>(H1); al1=pick<1>(L1); }
        else              { ah0=pick<2>(H0); al0=pick<2>(L0); ah1=pick<2>(H1); al1=pick<2>(L1); }
        if (m == 0) { A1h0=ah0; A1l0=al0; A1h1=ah1; A1l1=al1; }
        else        { A2h0=ah0; A2l0=al0; A2h1=ah1; A2l1=al1; }
    }

    // ---- init recurrence state (T1 = S from plane, bf16 precision) ----
    float U1[16], V1[16], P1[16], U2[16], V2[16], P2[16];
    #pragma unroll
    for (int i = 0; i < 16; ++i) {
        float dg = (rws[i] == colstar) ? 1.f : 0.f;
        float tv1 = bf2f(TA[w][colstar][rws[i]]);
        float tv2 = bf2f(TB[w][colstar][rws[i]]);
        V1[i] = tv1; V2[i] = tv2; U1[i] = dg; U2[i] = dg;
        P1[i] = fmaf(0.95518452f, tv1, 1.2986135f * dg);
        P2[i] = fmaf(0.95518452f, tv2, 1.2986135f * dg);
    }

    // dual-chain Chebyshev step: 4 MFMAs per matrix (A hi/lo x B bf16), b64 LDS ops
    auto STEP = [&](float coef, float (&W1)[16], float (&W2)[16], bool dostore) {
        bf16x8 B10 = rd8(&TA[w][c][8*h]);
        bf16x8 B11 = rd8(&TA[w][c][16 + 8*h]);
        bf16x8 B20 = rd8(&TB[w][c][8*h]);
        bf16x8 B21 = rd8(&TB[w][c][16 + 8*h]);
        f32x16 a1 = zz, a2 = zz;
        a1 = __builtin_amdgcn_mfma_f32_32x32x16_bf16(A1h0, B10, a1, 0,0,0);
        a2 = __builtin_amdgcn_mfma_f32_32x32x16_bf16(A2h0, B20, a2, 0,0,0);
        a1 = __builtin_amdgcn_mfma_f32_32x32x16_bf16(A1l0, B10, a1, 0,0,0);
        a2 = __builtin_amdgcn_mfma_f32_32x32x16_bf16(A2l0, B20, a2, 0,0,0);
        a1 = __builtin_amdgcn_mfma_f32_32x32x16_bf16(A1h1, B11, a1, 0,0,0);
        a2 = __builtin_amdgcn_mfma_f32_32x32x16_bf16(A2h1, B21, a2, 0,0,0);
        a1 = __builtin_amdgcn_mfma_f32_32x32x16_bf16(A1l1, B11, a1, 0,0,0);
        a2 = __builtin_amdgcn_mfma_f32_32x32x16_bf16(A2l1, B21, a2, 0,0,0);
        #pragma unroll
        for (int i = 0; i < 16; ++i) {
            float n1 = fmaf(2.f, a1[i], -W1[i]);
            float n2 = fmaf(2.f, a2[i], -W2[i]);
            W1[i] = n1; W2[i] = n2;
            P1[i] = fmaf(coef, n1, P1[i]);
            P2[i] = fmaf(coef, n2, P2[i]);
        }
        if (dostore) {
            #pragma unroll
            for (int q = 0; q < 4; ++q) {
                int r0 = rq[q];
                unsigned short b1[4], b2[4];
                #pragma unroll
                for (int e = 0; e < 4; ++e) {
                    b1[e] = bfb(W1[4*q+e]);
                    b2[e] = bfb(W2[4*q+e]);
                }
                *reinterpret_cast<uint2*>(&TA[w][colstar][r0]) =
                    make_uint2((unsigned)b1[0] | ((unsigned)b1[1] << 16),
                               (unsigned)b1[2] | ((unsigned)b1[3] << 16));
                *reinterpret_cast<uint2*>(&TB[w][colstar][r0]) =
                    make_uint2((unsigned)b2[0] | ((unsigned)b2[1] << 16),
                               (unsigned)b2[2] | ((unsigned)b2[3] << 16));
            }
        }
    };

    STEP(-0.22809412f, U1, U2, true);    // T2
    STEP( 0.07262391f, V1, V2, true);    // T3
    STEP(-0.02601347f, U1, U2, true);    // T4
    STEP( 0.00993906f, V1, V2, true);    // T5
    STEP(-0.00395568f, U1, U2, true);    // T6
    STEP( 0.00161931f, V1, V2, true);    // T7
    STEP(-0.00067670f, U1, U2, true);    // T8
    STEP( 0.00028728f, V1, V2, true);    // T9
    STEP(-0.00012348f, U1, U2, true);    // T10
    STEP( 0.00005361f, V1, V2, false);   // T11 (T12 dropped, proven R16)

    float s = 0.f;
    #pragma unroll
    for (int i = 0; i < 16; ++i) { float d = P1[i] - P2[i]; s = fmaf(d, d, s); }
    #pragma unroll
    for (int m = 32; m >= 1; m >>= 1)
        s += bperm((lane ^ m) << 2, s);
    if (lane == 0) bl[w] = valid * sqrtf(fmaxf(s, 0.f));

    __syncthreads();
    if (t == 0) {
        float sum = 0.f;
        #pragma unroll
        for (int i = 0; i < NW; ++i) sum += bl[i];
        if (part) part[blockIdx.x] = sum;   // plain store: no same-address RMW
        else atomicAdd(out, sum);           // fallback if ws too small
    }
}

// second-stage reduce: one block sums the per-block partials; ONE atomic total
// (atomicAdd, not store, so cold-path sentinels in out[0] are preserved).
__global__ __launch_bounds__(256)
void reduce_partials(const float* __restrict__ part, float* __restrict__ out, int n)
{
    __shared__ float sm[4];
    const int t = threadIdx.x;
    const int lane = t & 63, wv = t >> 6;
    float s = 0.f;
    for (int i = t; i < n; i += 256) s += part[i];
    #pragma unroll
    for (int m = 32; m >= 1; m >>= 1)
        s += __int_as_float(__builtin_amdgcn_ds_bpermute(((lane ^ m) << 2),
                                                         __float_as_int(s)));
    if (lane == 0) sm[wv] = s;
    __syncthreads();
    if (t == 0) atomicAdd(out, sm[0] + sm[1] + sm[2] + sm[3]);
}

extern "C" void kernel_launch(void* const* d_in, const int* in_sizes, int n_in,
                              void* d_out, int out_size, void* d_ws, size_t ws_size,
                              hipStream_t stream)
{
    const float* yhat = (const float*)d_in[0];
    const float* y    = (const float*)d_in[1];
    float* out = (float*)d_out;
    const int B = in_sizes[0] / 1024;   // 32*32 per matrix
    const int grid = (B + NW - 1) / NW;

    float* part = (ws_size >= (size_t)grid * sizeof(float)) ? (float*)d_ws : nullptr;

    (void)hipMemsetAsync(out, 0, sizeof(float), stream);
    hipLaunchKernelGGL(geo_loss_mfma, dim3(grid), dim3(128), 0, stream,
                       yhat, y, out, part, B);
    if (part)
        hipLaunchKernelGGL(reduce_partials, dim3(1), dim3(256), 0, stream,
                           part, out, grid);
}

// Round 22
// 85.485 us; speedup vs baseline: 2.7629x; 1.1687x over previous
//
#include <hip/hip_runtime.h>
#include <hip/hip_bf16.h>
#include <math.h>

#define NW 2   // samples per 128-thread block (1 per wave)

typedef __attribute__((ext_vector_type(8)))  short bf16x8;
typedef __attribute__((ext_vector_type(16))) float f32x16;
typedef float v2f __attribute__((ext_vector_type(2)));

__device__ __forceinline__ float bperm(int srcidx, float x) {
    return __int_as_float(__builtin_amdgcn_ds_bpermute(srcidx, __float_as_int(x)));
}
// f32 -> bf16 bits, RNE (manual, bit-deterministic: probes)
__device__ __forceinline__ unsigned f2bfu(float x) {
    unsigned u = __float_as_uint(x);
    return (u + 0x7fffu + ((u >> 16) & 1u)) >> 16;
}
__device__ __forceinline__ float bf2f(unsigned hb) { return __uint_as_float(hb << 16); }
__device__ __forceinline__ unsigned short bfb(float x) {
    __hip_bfloat16 b = __float2bfloat16(x);
    unsigned short u;
    __builtin_memcpy(&u, &b, sizeof(u));
    return u;
}
__device__ __forceinline__ void split(float x, unsigned short& hb, unsigned short& lb) {
    hb = bfb(x);
    float lo = x - bf2f(hb);
    lb = bfb(lo);
}
template <int JM>
__device__ __forceinline__ bf16x8 pick(const unsigned short (&s)[8]) {
    bf16x8 r;
    #pragma unroll
    for (int j = 0; j < 8; ++j) {
        int idx = (JM == 0) ? j : (JM == 1 ? (j ^ 4) : (7 - j));
        r[j] = (short)s[idx];
    }
    return r;
}
// two ds_read_b64 -> one bf16x8 (stride-36 planes: 2-way conflicts = free)
__device__ __forceinline__ bf16x8 rd8(const unsigned short* p) {
    uint2 a = *reinterpret_cast<const uint2*>(p);
    uint2 b = *reinterpret_cast<const uint2*>(p + 4);
    union { unsigned u[4]; bf16x8 v; } r;
    r.u[0] = a.x; r.u[1] = a.y; r.u[2] = b.x; r.u[3] = b.y;
    return r.v;
}
// packed fma d = a*b + c (proven syntax, R4-R8)
__device__ __forceinline__ v2f pkfma(v2f a, v2f b, v2f c) {
    v2f d;
    asm("v_pk_fma_f32 %0, %1, %2, %3" : "=v"(d) : "v"(a), "v"(b), "v"(c));
    return d;
}

// logm via Chebyshev deg-10 of log on [1,8]: S=(M-4.5I)/3.5, T_{k+1}=2*S*T_k-T_{k-1}.
// R20 structure (99.9us proven: partial-store + reduce, no same-address atomics).
// R21: (1) ALTERNATING-SIGN state -> recurrence/accum in v_pk_fma_f32 with NO neg
// modifier: stored_new = (+-2)*a + stored_old; LDS-store sign folds into free cvt
// src-modifier; coef signs are compile-time. Exact algebra. (2) 9 STEPs (T11
// dropped, proven R17/R18). (3) single-A (hi-only) MFMA for T6..T10: error
// <= 2^-9 * sum|c6..c10| ~ 1.3e-5/elem, invisible. Layout probes proven R10+.
__global__ __launch_bounds__(128, 1)
void geo_loss_mfma(const float* __restrict__ yhat, const float* __restrict__ y,
                   float* __restrict__ out, float* __restrict__ part, int B)
{
    __shared__ unsigned short TA[NW][32][36];   // chain-1 (yhat) T_k plane, bf16
    __shared__ unsigned short TB[NW][32][36];   // chain-2 (y)    T_k plane, bf16
    __shared__ float bl[NW];

    const int t    = threadIdx.x;
    const int w    = t >> 6;
    const int lane = t & 63;
    const int c    = lane & 31;
    const int h    = lane >> 5;

    int b = blockIdx.x * NW + w;
    const float valid = (b < B) ? 1.f : 0.f;
    if (b >= B) b = B - 1;

    const f32x16 zz = {0.f,0.f,0.f,0.f,0.f,0.f,0.f,0.f,0.f,0.f,0.f,0.f,0.f,0.f,0.f,0.f};
    float sent = 0.f;

    // ---- probe 1: relative A/B slot-labeling delta (6 hypotheses) ----
    bf16x8 pa;
    #pragma unroll
    for (int j = 0; j < 8; ++j) pa[j] = (short)f2bfu((float)(8*h + j + 1));
    int sel = -1;
    #pragma unroll
    for (int cand = 0; cand < 6; ++cand) {
        const int hfc = cand & 1, jmc = cand >> 1;
        bf16x8 pb;
        #pragma unroll
        for (int j = 0; j < 8; ++j) {
            int hh = hfc ? (1 - h) : h;
            int jj = (jmc == 0) ? j : (jmc == 1 ? (j ^ 4) : (7 - j));
            float lab = (float)(8*hh + jj + 1);
            pb[j] = (short)f2bfu(lab * lab);
        }
        f32x16 pr = __builtin_amdgcn_mfma_f32_32x32x16_bf16(pa, pb, zz, 0, 0, 0);
        if (sel < 0 && __ballot(pr[0] != 18496.f) == 0ull) sel = cand;
    }
    if (sel < 0) { sent += 1.0e10f; sel = 0; }
    const int hf = sel & 1, jm = sel >> 1;

    // ---- probe 2: C (lane,reg) -> row map (init-only) ----
    bf16x8 pa2, pb1;
    #pragma unroll
    for (int j = 0; j < 8; ++j) {
        pa2[j] = (short)f2bfu((float)(c + 1));
        pb1[j] = (short)f2bfu(1.f);
    }
    f32x16 r2 = __builtin_amdgcn_mfma_f32_32x32x16_bf16(pa2, pb1, zz, 0, 0, 0);
    int rws[16]; bool ok2 = true;
    #pragma unroll
    for (int i = 0; i < 16; ++i) {
        float q = r2[i] * 0.0625f;
        int ri = (int)(q + 0.5f);
        ok2 = ok2 && (fabsf(q - (float)ri) < 1e-3f) && ri >= 1 && ri <= 32;
        rws[i] = ri - 1;
    }
    if (__ballot(!ok2) != 0ull) {
        sent += 2.0e10f;
        #pragma unroll
        for (int i = 0; i < 16; ++i) rws[i] = (i & 3) + 8*(i >> 2) + 4*h;
    }

    // ---- probe 3: C lane -> col map ----
    f32x16 r3 = __builtin_amdgcn_mfma_f32_32x32x16_bf16(pb1, pa2, zz, 0, 0, 0);
    int colstar;
    {
        float q = r3[0] * 0.0625f;
        int ci = (int)(q + 0.5f);
        bool ok3 = (fabsf(q - (float)ci) < 1e-3f) && ci >= 1 && ci <= 32;
        colstar = ci - 1;
        if (__ballot(!ok3) != 0ull) { sent += 4.0e10f; colstar = c; }
    }

    // quad-contiguity; keep only rq[4] live through the loop
    bool qok = true;
    int rq[4];
    #pragma unroll
    for (int q = 0; q < 4; ++q) {
        rq[q] = rws[4*q];
        qok = qok && ((rws[4*q] & 3) == 0) && (rws[4*q+1] == rws[4*q]+1)
                  && (rws[4*q+2] == rws[4*q]+2) && (rws[4*q+3] == rws[4*q]+3);
    }
    if (__ballot(!qok) != 0ull) {
        sent += 8.0e10f;
        #pragma unroll
        for (int q = 0; q < 4; ++q) rq[q] = 8*q + 4*h;
    }
    if (lane == 0 && sent > 0.f) atomicAdd(out, sent);   // cold path only

    const float INV = 0.2857142857142857f;   // 1/3.5
    const int abase = 8 * (h ^ hf);

    // ---- load S rows; A-frags hi/lo in regs; stage bf16 S (=T1) to planes ----
    bf16x8 A1h0, A1l0, A1h1, A1l1, A2h0, A2l0, A2h1, A2l1;
    #pragma unroll
    for (int m = 0; m < 2; ++m) {
        const float* Mp = (m == 0 ? yhat : y) + ((size_t)b << 10);
        unsigned short H0[8], L0[8], H1[8], L1[8];
        const float4* p0 = reinterpret_cast<const float4*>(Mp + c*32 + abase);
        float4 q0 = p0[0], q1 = p0[1];
        float f0[8] = {q0.x,q0.y,q0.z,q0.w, q1.x,q1.y,q1.z,q1.w};
        const float4* p1 = reinterpret_cast<const float4*>(Mp + c*32 + 16 + abase);
        float4 q2 = p1[0], q3 = p1[1];
        float f1[8] = {q2.x,q2.y,q2.z,q2.w, q3.x,q3.y,q3.z,q3.w};
        #pragma unroll
        for (int e = 0; e < 8; ++e) {
            int k0 = abase + e, k1 = 16 + abase + e;
            float x0 = (f0[e] - ((k0 == c) ? 4.5f : 0.f)) * INV;
            float x1 = (f1[e] - ((k1 == c) ? 4.5f : 0.f)) * INV;
            split(x0, H0[e], L0[e]);
            split(x1, H1[e], L1[e]);
        }
        unsigned short (*pl)[36] = (m == 0) ? TA[w] : TB[w];
        *reinterpret_cast<uint2*>(&pl[c][abase]) =
            make_uint2((unsigned)H0[0] | ((unsigned)H0[1] << 16),
                       (unsigned)H0[2] | ((unsigned)H0[3] << 16));
        *reinterpret_cast<uint2*>(&pl[c][abase + 4]) =
            make_uint2((unsigned)H0[4] | ((unsigned)H0[5] << 16),
                       (unsigned)H0[6] | ((unsigned)H0[7] << 16));
        *reinterpret_cast<uint2*>(&pl[c][16 + abase]) =
            make_uint2((unsigned)H1[0] | ((unsigned)H1[1] << 16),
                       (unsigned)H1[2] | ((unsigned)H1[3] << 16));
        *reinterpret_cast<uint2*>(&pl[c][16 + abase + 4]) =
            make_uint2((unsigned)H1[4] | ((unsigned)H1[5] << 16),
                       (unsigned)H1[6] | ((unsigned)H1[7] << 16));
        bf16x8 ah0, al0, ah1, al1;
        if (jm == 0)      { ah0=pick<0>(H0); al0=pick<0>(L0); ah1=pick<0>(H1); al1=pick<0>(L1); }
        else if (jm == 1) { ah0=pick<1>(H0); al0=pick<1>(L0); ah1=pick<1>(H1); al1=pick<1>(L1); }
        else              { ah0=pick<2>(H0); al0=pick<2>(L0); ah1=pick<2>(H1); al1=pick<2>(L1); }
        if (m == 0) { A1h0=ah0; A1l0=al0; A1h1=ah1; A1l1=al1; }
        else        { A2h0=ah0; A2l0=al0; A2h1=ah1; A2l1=al1; }
    }

    // ---- init recurrence state (stored-sign state: U=+I, V=+S at s=+1) ----
    v2f U1[8], V1[8], P1[8], U2[8], V2[8], P2[8];
    #pragma unroll
    for (int i = 0; i < 16; ++i) {
        float dg = (rws[i] == colstar) ? 1.f : 0.f;
        float tv1 = bf2f(TA[w][colstar][rws[i]]);
        float tv2 = bf2f(TB[w][colstar][rws[i]]);
        V1[i >> 1][i & 1] = tv1;  V2[i >> 1][i & 1] = tv2;
        U1[i >> 1][i & 1] = dg;   U2[i >> 1][i & 1] = dg;
        P1[i >> 1][i & 1] = fmaf(0.95518452f, tv1, 1.2986135f * dg);
        P2[i >> 1][i & 1] = fmaf(0.95518452f, tv2, 1.2986135f * dg);
    }

    // Chebyshev step with alternating-sign state: stored_new = m2*a + stored_old
    // (m2 = +-2, compile-time); true T = sgn*stored_new; LDS gets bfb(+-stored)
    // (neg folds into cvt src-modifier); P += cp*stored (cp sign-adjusted).
    auto STEP = [&](float m2, float cp, bool negst, bool fullA,
                    v2f (&W1)[8], v2f (&W2)[8], bool dostore) {
        bf16x8 B10 = rd8(&TA[w][c][8*h]);
        bf16x8 B11 = rd8(&TA[w][c][16 + 8*h]);
        bf16x8 B20 = rd8(&TB[w][c][8*h]);
        bf16x8 B21 = rd8(&TB[w][c][16 + 8*h]);
        f32x16 a1 = zz, a2 = zz;
        a1 = __builtin_amdgcn_mfma_f32_32x32x16_bf16(A1h0, B10, a1, 0,0,0);
        a2 = __builtin_amdgcn_mfma_f32_32x32x16_bf16(A2h0, B20, a2, 0,0,0);
        if (fullA) {
            a1 = __builtin_amdgcn_mfma_f32_32x32x16_bf16(A1l0, B10, a1, 0,0,0);
            a2 = __builtin_amdgcn_mfma_f32_32x32x16_bf16(A2l0, B20, a2, 0,0,0);
        }
        a1 = __builtin_amdgcn_mfma_f32_32x32x16_bf16(A1h1, B11, a1, 0,0,0);
        a2 = __builtin_amdgcn_mfma_f32_32x32x16_bf16(A2h1, B21, a2, 0,0,0);
        if (fullA) {
            a1 = __builtin_amdgcn_mfma_f32_32x32x16_bf16(A1l1, B11, a1, 0,0,0);
            a2 = __builtin_amdgcn_mfma_f32_32x32x16_bf16(A2l1, B21, a2, 0,0,0);
        }
        v2f mt; mt[0] = m2; mt[1] = m2;
        v2f cv; cv[0] = cp; cv[1] = cp;
        #pragma unroll
        for (int k = 0; k < 8; ++k) {
            v2f a1v; a1v[0] = a1[2*k]; a1v[1] = a1[2*k+1];
            v2f a2v; a2v[0] = a2[2*k]; a2v[1] = a2[2*k+1];
            W1[k] = pkfma(mt, a1v, W1[k]);
            W2[k] = pkfma(mt, a2v, W2[k]);
            P1[k] = pkfma(cv, W1[k], P1[k]);
            P2[k] = pkfma(cv, W2[k], P2[k]);
        }
        if (dostore) {
            #pragma unroll
            for (int q = 0; q < 4; ++q) {
                int r0 = rq[q];
                unsigned short b1[4], b2[4];
                #pragma unroll
                for (int e = 0; e < 4; ++e) {
                    float w1e = W1[(4*q+e) >> 1][(4*q+e) & 1];
                    float w2e = W2[(4*q+e) >> 1][(4*q+e) & 1];
                    if (negst) { w1e = -w1e; w2e = -w2e; }  // free cvt src-mod
                    b1[e] = bfb(w1e);
                    b2[e] = bfb(w2e);
                }
                *reinterpret_cast<uint2*>(&TA[w][colstar][r0]) =
                    make_uint2((unsigned)b1[0] | ((unsigned)b1[1] << 16),
                               (unsigned)b1[2] | ((unsigned)b1[3] << 16));
                *reinterpret_cast<uint2*>(&TB[w][colstar][r0]) =
                    make_uint2((unsigned)b2[0] | ((unsigned)b2[1] << 16),
                               (unsigned)b2[2] | ((unsigned)b2[3] << 16));
            }
        }
    };

    // sign schedule: U updates (T2,T4,T6,T8,T10) s = -,+,-,+,-;
    //                V updates (T3,T5,T7,T9)     s = -,+,-,+.
    // cp = c_k * s_new;  m2 = 2*s_new;  negst = (s_new < 0).
    STEP(-2.f, +0.22809412f, true,  true,  U1, U2, true);   // T2  (c2=-0.22809412)
    STEP(-2.f, -0.07262391f, true,  true,  V1, V2, true);   // T3  (c3=+0.07262391)
    STEP(+2.f, -0.02601347f, false, true,  U1, U2, true);   // T4
    STEP(+2.f, +0.00993906f, false, true,  V1, V2, true);   // T5
    STEP(-2.f, +0.00395568f, true,  false, U1, U2, true);   // T6  (single-A tail)
    STEP(-2.f, -0.00161931f, true,  false, V1, V2, true);   // T7
    STEP(+2.f, -0.00067670f, false, false, U1, U2, true);   // T8
    STEP(+2.f, +0.00028728f, false, false, V1, V2, true);   // T9
    STEP(-2.f, +0.00012348f, true,  false, U1, U2, false);  // T10 (T11,T12 dropped)

    float s = 0.f;
    #pragma unroll
    for (int k = 0; k < 8; ++k) {
        v2f d = P1[k] - P2[k];
        s = fmaf(d[0], d[0], s);
        s = fmaf(d[1], d[1], s);
    }
    #pragma unroll
    for (int m = 32; m >= 1; m >>= 1)
        s += bperm((lane ^ m) << 2, s);
    if (lane == 0) bl[w] = valid * sqrtf(fmaxf(s, 0.f));

    __syncthreads();
    if (t == 0) {
        float sum = 0.f;
        #pragma unroll
        for (int i = 0; i < NW; ++i) sum += bl[i];
        if (part) part[blockIdx.x] = sum;   // plain store: no same-address RMW
        else atomicAdd(out, sum);           // fallback if ws too small
    }
}

// second-stage reduce: one block sums the per-block partials; ONE atomic total
// (atomicAdd, not store, so cold-path sentinels in out[0] are preserved).
__global__ __launch_bounds__(256)
void reduce_partials(const float* __restrict__ part, float* __restrict__ out, int n)
{
    __shared__ float sm[4];
    const int t = threadIdx.x;
    const int lane = t & 63, wv = t >> 6;
    float s = 0.f;
    for (int i = t; i < n; i += 256) s += part[i];
    #pragma unroll
    for (int m = 32; m >= 1; m >>= 1)
        s += __int_as_float(__builtin_amdgcn_ds_bpermute(((lane ^ m) << 2),
                                                         __float_as_int(s)));
    if (lane == 0) sm[wv] = s;
    __syncthreads();
    if (t == 0) atomicAdd(out, sm[0] + sm[1] + sm[2] + sm[3]);
}

extern "C" void kernel_launch(void* const* d_in, const int* in_sizes, int n_in,
                              void* d_out, int out_size, void* d_ws, size_t ws_size,
                              hipStream_t stream)
{
    const float* yhat = (const float*)d_in[0];
    const float* y    = (const float*)d_in[1];
    float* out = (float*)d_out;
    const int B = in_sizes[0] / 1024;   // 32*32 per matrix
    const int grid = (B + NW - 1) / NW;

    float* part = (ws_size >= (size_t)grid * sizeof(float)) ? (float*)d_ws : nullptr;

    (void)hipMemsetAsync(out, 0, sizeof(float), stream);
    hipLaunchKernelGGL(geo_loss_mfma, dim3(grid), dim3(128), 0, stream,
                       yhat, y, out, part, B);
    if (part)
        hipLaunchKernelGGL(reduce_partials, dim3(1), dim3(256), 0, stream,
                           part, out, grid);
}

// Round 23
// 84.790 us; speedup vs baseline: 2.7855x; 1.0082x over previous
//
#include <hip/hip_runtime.h>
#include <hip/hip_bf16.h>
#include <math.h>

#define NW 2   // samples per 128-thread block (1 per wave)

typedef __attribute__((ext_vector_type(8)))  short bf16x8;
typedef __attribute__((ext_vector_type(16))) float f32x16;
typedef float v2f __attribute__((ext_vector_type(2)));

__device__ __forceinline__ float bperm(int srcidx, float x) {
    return __int_as_float(__builtin_amdgcn_ds_bpermute(srcidx, __float_as_int(x)));
}
// f32 -> bf16 bits, RNE (manual, bit-deterministic: probes)
__device__ __forceinline__ unsigned f2bfu(float x) {
    unsigned u = __float_as_uint(x);
    return (u + 0x7fffu + ((u >> 16) & 1u)) >> 16;
}
__device__ __forceinline__ float bf2f(unsigned hb) { return __uint_as_float(hb << 16); }
__device__ __forceinline__ unsigned short bfb(float x) {
    __hip_bfloat16 b = __float2bfloat16(x);
    unsigned short u;
    __builtin_memcpy(&u, &b, sizeof(u));
    return u;
}
__device__ __forceinline__ void split(float x, unsigned short& hb, unsigned short& lb) {
    hb = bfb(x);
    float lo = x - bf2f(hb);
    lb = bfb(lo);
}
template <int JM>
__device__ __forceinline__ bf16x8 pick(const unsigned short (&s)[8]) {
    bf16x8 r;
    #pragma unroll
    for (int j = 0; j < 8; ++j) {
        int idx = (JM == 0) ? j : (JM == 1 ? (j ^ 4) : (7 - j));
        r[j] = (short)s[idx];
    }
    return r;
}
// two ds_read_b64 -> one bf16x8 (stride-36 planes: 2-way conflicts = free)
__device__ __forceinline__ bf16x8 rd8(const unsigned short* p) {
    uint2 a = *reinterpret_cast<const uint2*>(p);
    uint2 b = *reinterpret_cast<const uint2*>(p + 4);
    union { unsigned u[4]; bf16x8 v; } r;
    r.u[0] = a.x; r.u[1] = a.y; r.u[2] = b.x; r.u[3] = b.y;
    return r.v;
}
// packed fma d = a*b + c (proven syntax, R4-R8, R21)
__device__ __forceinline__ v2f pkfma(v2f a, v2f b, v2f c) {
    v2f d;
    asm("v_pk_fma_f32 %0, %1, %2, %3" : "=v"(d) : "v"(a), "v"(b), "v"(c));
    return d;
}

// logm via Chebyshev deg-8 of log on [1,8]: S=(M-4.5I)/3.5, T_{k+1}=2*S*T_k-T_{k-1}.
// R21 structure proven 85.5us/absmax 0.0 (partial-store+reduce, alternating-sign
// pk-fma state, single-A tail). R22: (1) T9,T10 dropped -> 7 STEPs; worst-case
// SYSTEMATIC loss error (|c9|+|c10|)*sqrt(32)*2*16384 ~ 76 << threshold 1228 and
// << output bf16 quantum ~512. (2) per-wave partial store (no __syncthreads/bl[]).
// Layout discovered by 3 one-MFMA probes (proven R10+).
__global__ __launch_bounds__(128, 1)
void geo_loss_mfma(const float* __restrict__ yhat, const float* __restrict__ y,
                   float* __restrict__ out, float* __restrict__ part, int B)
{
    __shared__ unsigned short TA[NW][32][36];   // chain-1 (yhat) T_k plane, bf16
    __shared__ unsigned short TB[NW][32][36];   // chain-2 (y)    T_k plane, bf16

    const int t    = threadIdx.x;
    const int w    = t >> 6;
    const int lane = t & 63;
    const int c    = lane & 31;
    const int h    = lane >> 5;

    int b = blockIdx.x * NW + w;
    const float valid = (b < B) ? 1.f : 0.f;
    if (b >= B) b = B - 1;

    const f32x16 zz = {0.f,0.f,0.f,0.f,0.f,0.f,0.f,0.f,0.f,0.f,0.f,0.f,0.f,0.f,0.f,0.f};
    float sent = 0.f;

    // ---- probe 1: relative A/B slot-labeling delta (6 hypotheses) ----
    bf16x8 pa;
    #pragma unroll
    for (int j = 0; j < 8; ++j) pa[j] = (short)f2bfu((float)(8*h + j + 1));
    int sel = -1;
    #pragma unroll
    for (int cand = 0; cand < 6; ++cand) {
        const int hfc = cand & 1, jmc = cand >> 1;
        bf16x8 pb;
        #pragma unroll
        for (int j = 0; j < 8; ++j) {
            int hh = hfc ? (1 - h) : h;
            int jj = (jmc == 0) ? j : (jmc == 1 ? (j ^ 4) : (7 - j));
            float lab = (float)(8*hh + jj + 1);
            pb[j] = (short)f2bfu(lab * lab);
        }
        f32x16 pr = __builtin_amdgcn_mfma_f32_32x32x16_bf16(pa, pb, zz, 0, 0, 0);
        if (sel < 0 && __ballot(pr[0] != 18496.f) == 0ull) sel = cand;
    }
    if (sel < 0) { sent += 1.0e10f; sel = 0; }
    const int hf = sel & 1, jm = sel >> 1;

    // ---- probe 2: C (lane,reg) -> row map (init-only) ----
    bf16x8 pa2, pb1;
    #pragma unroll
    for (int j = 0; j < 8; ++j) {
        pa2[j] = (short)f2bfu((float)(c + 1));
        pb1[j] = (short)f2bfu(1.f);
    }
    f32x16 r2 = __builtin_amdgcn_mfma_f32_32x32x16_bf16(pa2, pb1, zz, 0, 0, 0);
    int rws[16]; bool ok2 = true;
    #pragma unroll
    for (int i = 0; i < 16; ++i) {
        float q = r2[i] * 0.0625f;
        int ri = (int)(q + 0.5f);
        ok2 = ok2 && (fabsf(q - (float)ri) < 1e-3f) && ri >= 1 && ri <= 32;
        rws[i] = ri - 1;
    }
    if (__ballot(!ok2) != 0ull) {
        sent += 2.0e10f;
        #pragma unroll
        for (int i = 0; i < 16; ++i) rws[i] = (i & 3) + 8*(i >> 2) + 4*h;
    }

    // ---- probe 3: C lane -> col map ----
    f32x16 r3 = __builtin_amdgcn_mfma_f32_32x32x16_bf16(pb1, pa2, zz, 0, 0, 0);
    int colstar;
    {
        float q = r3[0] * 0.0625f;
        int ci = (int)(q + 0.5f);
        bool ok3 = (fabsf(q - (float)ci) < 1e-3f) && ci >= 1 && ci <= 32;
        colstar = ci - 1;
        if (__ballot(!ok3) != 0ull) { sent += 4.0e10f; colstar = c; }
    }

    // quad-contiguity; keep only rq[4] live through the loop
    bool qok = true;
    int rq[4];
    #pragma unroll
    for (int q = 0; q < 4; ++q) {
        rq[q] = rws[4*q];
        qok = qok && ((rws[4*q] & 3) == 0) && (rws[4*q+1] == rws[4*q]+1)
                  && (rws[4*q+2] == rws[4*q]+2) && (rws[4*q+3] == rws[4*q]+3);
    }
    if (__ballot(!qok) != 0ull) {
        sent += 8.0e10f;
        #pragma unroll
        for (int q = 0; q < 4; ++q) rq[q] = 8*q + 4*h;
    }
    if (lane == 0 && sent > 0.f) atomicAdd(out, sent);   // cold path only

    const float INV = 0.2857142857142857f;   // 1/3.5
    const int abase = 8 * (h ^ hf);

    // ---- load S rows; A-frags hi/lo in regs; stage bf16 S (=T1) to planes ----
    bf16x8 A1h0, A1l0, A1h1, A1l1, A2h0, A2l0, A2h1, A2l1;
    #pragma unroll
    for (int m = 0; m < 2; ++m) {
        const float* Mp = (m == 0 ? yhat : y) + ((size_t)b << 10);
        unsigned short H0[8], L0[8], H1[8], L1[8];
        const float4* p0 = reinterpret_cast<const float4*>(Mp + c*32 + abase);
        float4 q0 = p0[0], q1 = p0[1];
        float f0[8] = {q0.x,q0.y,q0.z,q0.w, q1.x,q1.y,q1.z,q1.w};
        const float4* p1 = reinterpret_cast<const float4*>(Mp + c*32 + 16 + abase);
        float4 q2 = p1[0], q3 = p1[1];
        float f1[8] = {q2.x,q2.y,q2.z,q2.w, q3.x,q3.y,q3.z,q3.w};
        #pragma unroll
        for (int e = 0; e < 8; ++e) {
            int k0 = abase + e, k1 = 16 + abase + e;
            float x0 = (f0[e] - ((k0 == c) ? 4.5f : 0.f)) * INV;
            float x1 = (f1[e] - ((k1 == c) ? 4.5f : 0.f)) * INV;
            split(x0, H0[e], L0[e]);
            split(x1, H1[e], L1[e]);
        }
        unsigned short (*pl)[36] = (m == 0) ? TA[w] : TB[w];
        *reinterpret_cast<uint2*>(&pl[c][abase]) =
            make_uint2((unsigned)H0[0] | ((unsigned)H0[1] << 16),
                       (unsigned)H0[2] | ((unsigned)H0[3] << 16));
        *reinterpret_cast<uint2*>(&pl[c][abase + 4]) =
            make_uint2((unsigned)H0[4] | ((unsigned)H0[5] << 16),
                       (unsigned)H0[6] | ((unsigned)H0[7] << 16));
        *reinterpret_cast<uint2*>(&pl[c][16 + abase]) =
            make_uint2((unsigned)H1[0] | ((unsigned)H1[1] << 16),
                       (unsigned)H1[2] | ((unsigned)H1[3] << 16));
        *reinterpret_cast<uint2*>(&pl[c][16 + abase + 4]) =
            make_uint2((unsigned)H1[4] | ((unsigned)H1[5] << 16),
                       (unsigned)H1[6] | ((unsigned)H1[7] << 16));
        bf16x8 ah0, al0, ah1, al1;
        if (jm == 0)      { ah0=pick<0>(H0); al0=pick<0>(L0); ah1=pick<0>(H1); al1=pick<0>(L1); }
        else if (jm == 1) { ah0=pick<1>(H0); al0=pick<1>(L0); ah1=pick<1>(H1); al1=pick<1>(L1); }
        else              { ah0=pick<2>(H0); al0=pick<2>(L0); ah1=pick<2>(H1); al1=pick<2>(L1); }
        if (m == 0) { A1h0=ah0; A1l0=al0; A1h1=ah1; A1l1=al1; }
        else        { A2h0=ah0; A2l0=al0; A2h1=ah1; A2l1=al1; }
    }

    // ---- init recurrence state (stored-sign state: U=+I, V=+S at s=+1) ----
    v2f U1[8], V1[8], P1[8], U2[8], V2[8], P2[8];
    #pragma unroll
    for (int i = 0; i < 16; ++i) {
        float dg = (rws[i] == colstar) ? 1.f : 0.f;
        float tv1 = bf2f(TA[w][colstar][rws[i]]);
        float tv2 = bf2f(TB[w][colstar][rws[i]]);
        V1[i >> 1][i & 1] = tv1;  V2[i >> 1][i & 1] = tv2;
        U1[i >> 1][i & 1] = dg;   U2[i >> 1][i & 1] = dg;
        P1[i >> 1][i & 1] = fmaf(0.95518452f, tv1, 1.2986135f * dg);
        P2[i >> 1][i & 1] = fmaf(0.95518452f, tv2, 1.2986135f * dg);
    }

    // Chebyshev step with alternating-sign state: stored_new = m2*a + stored_old
    // (m2 = +-2, compile-time); LDS gets bfb(+-stored) (neg = free cvt src-mod);
    // P += cp*stored (cp sign-adjusted at compile time).
    auto STEP = [&](float m2, float cp, bool negst, bool fullA,
                    v2f (&W1)[8], v2f (&W2)[8], bool dostore) {
        bf16x8 B10 = rd8(&TA[w][c][8*h]);
        bf16x8 B11 = rd8(&TA[w][c][16 + 8*h]);
        bf16x8 B20 = rd8(&TB[w][c][8*h]);
        bf16x8 B21 = rd8(&TB[w][c][16 + 8*h]);
        f32x16 a1 = zz, a2 = zz;
        a1 = __builtin_amdgcn_mfma_f32_32x32x16_bf16(A1h0, B10, a1, 0,0,0);
        a2 = __builtin_amdgcn_mfma_f32_32x32x16_bf16(A2h0, B20, a2, 0,0,0);
        if (fullA) {
            a1 = __builtin_amdgcn_mfma_f32_32x32x16_bf16(A1l0, B10, a1, 0,0,0);
            a2 = __builtin_amdgcn_mfma_f32_32x32x16_bf16(A2l0, B20, a2, 0,0,0);
        }
        a1 = __builtin_amdgcn_mfma_f32_32x32x16_bf16(A1h1, B11, a1, 0,0,0);
        a2 = __builtin_amdgcn_mfma_f32_32x32x16_bf16(A2h1, B21, a2, 0,0,0);
        if (fullA) {
            a1 = __builtin_amdgcn_mfma_f32_32x32x16_bf16(A1l1, B11, a1, 0,0,0);
            a2 = __builtin_amdgcn_mfma_f32_32x32x16_bf16(A2l1, B21, a2, 0,0,0);
        }
        v2f mt; mt[0] = m2; mt[1] = m2;
        v2f cv; cv[0] = cp; cv[1] = cp;
        #pragma unroll
        for (int k = 0; k < 8; ++k) {
            v2f a1v; a1v[0] = a1[2*k]; a1v[1] = a1[2*k+1];
            v2f a2v; a2v[0] = a2[2*k]; a2v[1] = a2[2*k+1];
            W1[k] = pkfma(mt, a1v, W1[k]);
            W2[k] = pkfma(mt, a2v, W2[k]);
            P1[k] = pkfma(cv, W1[k], P1[k]);
            P2[k] = pkfma(cv, W2[k], P2[k]);
        }
        if (dostore) {
            #pragma unroll
            for (int q = 0; q < 4; ++q) {
                int r0 = rq[q];
                unsigned short b1[4], b2[4];
                #pragma unroll
                for (int e = 0; e < 4; ++e) {
                    float w1e = W1[(4*q+e) >> 1][(4*q+e) & 1];
                    float w2e = W2[(4*q+e) >> 1][(4*q+e) & 1];
                    if (negst) { w1e = -w1e; w2e = -w2e; }  // free cvt src-mod
                    b1[e] = bfb(w1e);
                    b2[e] = bfb(w2e);
                }
                *reinterpret_cast<uint2*>(&TA[w][colstar][r0]) =
                    make_uint2((unsigned)b1[0] | ((unsigned)b1[1] << 16),
                               (unsigned)b1[2] | ((unsigned)b1[3] << 16));
                *reinterpret_cast<uint2*>(&TB[w][colstar][r0]) =
                    make_uint2((unsigned)b2[0] | ((unsigned)b2[1] << 16),
                               (unsigned)b2[2] | ((unsigned)b2[3] << 16));
            }
        }
    };

    // sign schedule: U updates (T2,T4,T6,T8) s = -,+,-,+; V updates (T3,T5,T7) s = -,+,-.
    // cp = c_k * s_new;  m2 = 2*s_new;  negst = (s_new < 0).
    STEP(-2.f, +0.22809412f, true,  true,  U1, U2, true);   // T2 (c2=-0.22809412)
    STEP(-2.f, -0.07262391f, true,  true,  V1, V2, true);   // T3 (c3=+0.07262391)
    STEP(+2.f, -0.02601347f, false, true,  U1, U2, true);   // T4
    STEP(+2.f, +0.00993906f, false, true,  V1, V2, true);   // T5
    STEP(-2.f, +0.00395568f, true,  false, U1, U2, true);   // T6 (single-A tail)
    STEP(-2.f, -0.00161931f, true,  false, V1, V2, true);   // T7
    STEP(+2.f, -0.00067670f, false, false, U1, U2, false);  // T8 (T9..T12 dropped)

    float s = 0.f;
    #pragma unroll
    for (int k = 0; k < 8; ++k) {
        v2f d = P1[k] - P2[k];
        s = fmaf(d[0], d[0], s);
        s = fmaf(d[1], d[1], s);
    }
    #pragma unroll
    for (int m = 32; m >= 1; m >>= 1)
        s += bperm((lane ^ m) << 2, s);
    // per-wave partial store: no __syncthreads, no same-address RMW
    if (lane == 0) {
        float v = valid * sqrtf(fmaxf(s, 0.f));
        if (part) part[blockIdx.x * NW + w] = v;
        else atomicAdd(out, v);            // fallback if ws too small
    }
}

// second-stage reduce: one block sums the per-wave partials; ONE atomic total
// (atomicAdd, not store, so cold-path sentinels in out[0] are preserved).
__global__ __launch_bounds__(256)
void reduce_partials(const float* __restrict__ part, float* __restrict__ out, int n)
{
    __shared__ float sm[4];
    const int t = threadIdx.x;
    const int lane = t & 63, wv = t >> 6;
    float s = 0.f;
    for (int i = t; i < n; i += 256) s += part[i];
    #pragma unroll
    for (int m = 32; m >= 1; m >>= 1)
        s += __int_as_float(__builtin_amdgcn_ds_bpermute(((lane ^ m) << 2),
                                                         __float_as_int(s)));
    if (lane == 0) sm[wv] = s;
    __syncthreads();
    if (t == 0) atomicAdd(out, sm[0] + sm[1] + sm[2] + sm[3]);
}

extern "C" void kernel_launch(void* const* d_in, const int* in_sizes, int n_in,
                              void* d_out, int out_size, void* d_ws, size_t ws_size,
                              hipStream_t stream)
{
    const float* yhat = (const float*)d_in[0];
    const float* y    = (const float*)d_in[1];
    float* out = (float*)d_out;
    const int B = in_sizes[0] / 1024;   // 32*32 per matrix
    const int grid = (B + NW - 1) / NW;
    const int nPart = grid * NW;

    float* part = (ws_size >= (size_t)nPart * sizeof(float)) ? (float*)d_ws : nullptr;

    (void)hipMemsetAsync(out, 0, sizeof(float), stream);
    hipLaunchKernelGGL(geo_loss_mfma, dim3(grid), dim3(128), 0, stream,
                       yhat, y, out, part, B);
    if (part)
        hipLaunchKernelGGL(reduce_partials, dim3(1), dim3(256), 0, stream,
                           part, out, nPart);
}